// Round 4
// baseline (175.492 us; speedup 1.0000x reference)
//
#include <hip/hip_runtime.h>

#define SEQ     2048
#define BATCH   64
#define ENC_HID 1024
#define DEC_HID 1024
#define ATT_D   512
#define CHUNK   32
#define NCHUNK  (SEQ / CHUNK)   /* 64 */
#define SPW     (CHUNK / 4)     /* scores per wave = 8 */
#define L2E     1.4426950408889634f

// ---------------------------------------------------------------------------
// fast tanh: tanh(x) = 1 - 2/(1 + exp(2x)); saturates correctly for large |x|
__device__ __forceinline__ float fast_tanh(float x) {
    float e = __builtin_amdgcn_exp2f(x * 2.8853900817779268f);
    return 1.0f - 2.0f * __builtin_amdgcn_rcpf(1.0f + e);
}

// ---------------------------------------------------------------------------
// Kernel 1: dec_att[b][a] = sum_k dec_out[b][k] * W_dec[a][k]  (one wave/output)
__global__ __launch_bounds__(256) void k_dec_att(const float* __restrict__ dec_out,
                                                 const float* __restrict__ W_dec,
                                                 float* __restrict__ dec_att) {
    int w    = blockIdx.x * 4 + (threadIdx.x >> 6);
    int lane = threadIdx.x & 63;
    int b = w >> 9;
    int a = w & (ATT_D - 1);
    const float4* wd = (const float4*)(W_dec + (size_t)a * DEC_HID);
    const float4* dd = (const float4*)(dec_out + (size_t)b * DEC_HID);
    float acc = 0.f;
#pragma unroll
    for (int j = 0; j < 4; ++j) {
        int idx = j * 64 + lane;
        float4 x = wd[idx];
        float4 y = dd[idx];
        acc += x.x * y.x + x.y * y.y + x.z * y.z + x.w * y.w;
    }
#pragma unroll
    for (int off = 32; off; off >>= 1) acc += __shfl_xor(acc, off, 64);
    if (lane == 0) dec_att[(size_t)b * ATT_D + a] = acc;
}

// ---------------------------------------------------------------------------
// Kernel 2 (fused): per (b, s-chunk of CHUNK=32):
//   phase A: scores for the 32 s (raw scores also written for the weights output)
//   chunk-local softmax stats
//   phase B: unnormalized exp-weighted partial context from enc_outs
// __launch_bounds__(256, 8): force VGPR<=64 so 8 blocks/CU stay resident.
__global__ __launch_bounds__(256, 8) void k_fused(
        const float* __restrict__ enc_att,    // (SEQ, B, ATT_D)
        const float* __restrict__ enc_outs,   // (SEQ, B, ENC_HID)
        const float* __restrict__ dec_att,    // (B, ATT_D)
        const float* __restrict__ att_v,      // (ATT_D)
        float* __restrict__ scores_raw,       // (B, SEQ)  = d_out weights slot
        float* __restrict__ pctx,             // (B*NCHUNK, ENC_HID)
        float* __restrict__ maxsum)           // (B*NCHUNK, 2)
{
    __shared__ float sc[CHUNK];
    __shared__ float wl[CHUNK];
    int bid   = blockIdx.x;
    int b     = bid >> 6;                 // / NCHUNK
    int chunk = bid & (NCHUNK - 1);
    int s0    = chunk * CHUNK;
    int t     = threadIdx.x;
    int wv    = t >> 6, lane = t & 63;

    // per-lane constants for the score dot product
    const float4* da = (const float4*)(dec_att + (size_t)b * ATT_D);
    const float4* av = (const float4*)att_v;
    float4 d0 = da[lane], d1 = da[64 + lane];
    float4 v0 = av[lane], v1 = av[64 + lane];

    // phase A: each wave computes SPW=8 of the 32 chunk scores
#pragma unroll 2
    for (int i = 0; i < SPW; ++i) {
        int sl = wv * SPW + i;
        int s  = s0 + sl;
        const float4* ea = (const float4*)(enc_att + ((size_t)s * BATCH + b) * ATT_D);
        float4 e0 = ea[lane], e1 = ea[64 + lane];
        float acc = fast_tanh(e0.x + d0.x) * v0.x
                  + fast_tanh(e0.y + d0.y) * v0.y
                  + fast_tanh(e0.z + d0.z) * v0.z
                  + fast_tanh(e0.w + d0.w) * v0.w
                  + fast_tanh(e1.x + d1.x) * v1.x
                  + fast_tanh(e1.y + d1.y) * v1.y
                  + fast_tanh(e1.z + d1.z) * v1.z
                  + fast_tanh(e1.w + d1.w) * v1.w;
#pragma unroll
        for (int off = 32; off; off >>= 1) acc += __shfl_xor(acc, off, 64);
        if (lane == 0) {
            sc[sl] = acc;
            scores_raw[(size_t)b * SEQ + s] = acc;
        }
    }
    __syncthreads();

    // chunk-local softmax stats (wave 0; lanes 0..31 hold the 32 scores)
    if (wv == 0) {
        float v = (lane < CHUNK) ? sc[lane] : -3.4e38f;
        float m = v;
#pragma unroll
        for (int off = 32; off; off >>= 1) m = fmaxf(m, __shfl_xor(m, off, 64));
        float u = (lane < CHUNK) ? __builtin_amdgcn_exp2f((v - m) * L2E) : 0.f;
        if (lane < CHUNK) wl[lane] = u;
        float ssum = u;
#pragma unroll
        for (int off = 32; off; off >>= 1) ssum += __shfl_xor(ssum, off, 64);
        if (lane == 0) {
            maxsum[2 * bid]     = m;
            maxsum[2 * bid + 1] = ssum;
        }
    }
    __syncthreads();

    // phase B: unnormalized partial context over this chunk's 32 s
    const float4* base = (const float4*)enc_outs;
    float4 acc = {0.f, 0.f, 0.f, 0.f};
#pragma unroll 4
    for (int i = 0; i < CHUNK; ++i) {
        size_t idx = ((size_t)(s0 + i) * BATCH + b) * (ENC_HID / 4) + t;
        float4 e = base[idx];
        float w = wl[i];
        acc.x += w * e.x; acc.y += w * e.y; acc.z += w * e.z; acc.w += w * e.w;
    }
    ((float4*)(pctx + (size_t)bid * ENC_HID))[t] = acc;
}

// ---------------------------------------------------------------------------
// Kernel 3: per b — combine NCHUNK=64 chunk partials (flash rescale) + normalize weights
__global__ __launch_bounds__(256) void k_final(
        const float* __restrict__ pctx,
        const float* __restrict__ maxsum,
        float* __restrict__ context,   // (B, ENC_HID)
        float* __restrict__ weights)   // (B, SEQ): raw scores in, softmax out
{
    __shared__ float scale[NCHUNK];
    __shared__ float gv[2];
    int b = blockIdx.x;
    int t = threadIdx.x;
    int wv = t >> 6, lane = t & 63;

    if (wv == 0) {
        // exactly 64 chunks -> one per lane
        float m = maxsum[2 * (b * NCHUNK + lane)];
        float s = maxsum[2 * (b * NCHUNK + lane) + 1];
        float gm = m;
#pragma unroll
        for (int off = 32; off; off >>= 1) gm = fmaxf(gm, __shfl_xor(gm, off, 64));
        float sc_ = __builtin_amdgcn_exp2f((m - gm) * L2E);
        float e = s * sc_;
#pragma unroll
        for (int off = 32; off; off >>= 1) e += __shfl_xor(e, off, 64);
        scale[lane] = sc_;
        if (lane == 0) { gv[0] = gm; gv[1] = 1.0f / e; }
    }
    __syncthreads();
    float gm = gv[0], inv = gv[1];

    float4 acc = {0.f, 0.f, 0.f, 0.f};
#pragma unroll 8
    for (int c = 0; c < NCHUNK; ++c) {
        float4 e = ((const float4*)(pctx + ((size_t)b * NCHUNK + c) * ENC_HID))[t];
        float s = scale[c];
        acc.x += s * e.x; acc.y += s * e.y; acc.z += s * e.z; acc.w += s * e.w;
    }
    acc.x *= inv; acc.y *= inv; acc.z *= inv; acc.w *= inv;
    ((float4*)(context + (size_t)b * ENC_HID))[t] = acc;

    float4* wrow = (float4*)(weights + (size_t)b * SEQ);
#pragma unroll
    for (int j = 0; j < 2; ++j) {
        float4 x = wrow[j * 256 + t];
        x.x = __builtin_amdgcn_exp2f((x.x - gm) * L2E) * inv;
        x.y = __builtin_amdgcn_exp2f((x.y - gm) * L2E) * inv;
        x.z = __builtin_amdgcn_exp2f((x.z - gm) * L2E) * inv;
        x.w = __builtin_amdgcn_exp2f((x.w - gm) * L2E) * inv;
        wrow[j * 256 + t] = x;
    }
}

// ---------------------------------------------------------------------------
// Fallback path (tiny ws): scores -> softmax -> zero+atomic context
__global__ __launch_bounds__(256) void k_scores(const float* __restrict__ enc_att,
                                                const float* __restrict__ dec_att,
                                                const float* __restrict__ att_v,
                                                float* __restrict__ scores) {
    int w    = blockIdx.x * 4 + (threadIdx.x >> 6);
    int lane = threadIdx.x & 63;
    int b = w & (BATCH - 1);
    int s = w >> 6;
    const float4* ea = (const float4*)(enc_att + ((size_t)s * BATCH + b) * ATT_D);
    const float4* da = (const float4*)(dec_att + (size_t)b * ATT_D);
    const float4* av = (const float4*)att_v;
    float acc = 0.f;
#pragma unroll
    for (int j = 0; j < 2; ++j) {
        int idx = j * 64 + lane;
        float4 e = ea[idx];
        float4 d = da[idx];
        float4 v = av[idx];
        acc += fast_tanh(e.x + d.x) * v.x + fast_tanh(e.y + d.y) * v.y
             + fast_tanh(e.z + d.z) * v.z + fast_tanh(e.w + d.w) * v.w;
    }
#pragma unroll
    for (int off = 32; off; off >>= 1) acc += __shfl_xor(acc, off, 64);
    if (lane == 0) scores[(size_t)b * SEQ + s] = acc;
}

__global__ __launch_bounds__(256) void k_softmax(float* __restrict__ scores) {
    __shared__ float red[8];
    int b = blockIdx.x;
    int t = threadIdx.x;
    int lane = t & 63, wv = t >> 6;
    float4* row = (float4*)(scores + (size_t)b * SEQ);
    float4 x0 = row[t];
    float4 x1 = row[t + 256];
    float mx = fmaxf(fmaxf(fmaxf(x0.x, x0.y), fmaxf(x0.z, x0.w)),
                     fmaxf(fmaxf(x1.x, x1.y), fmaxf(x1.z, x1.w)));
#pragma unroll
    for (int off = 32; off; off >>= 1) mx = fmaxf(mx, __shfl_xor(mx, off, 64));
    if (lane == 0) red[wv] = mx;
    __syncthreads();
    mx = fmaxf(fmaxf(red[0], red[1]), fmaxf(red[2], red[3]));
    float4 e0, e1;
    e0.x = __builtin_amdgcn_exp2f((x0.x - mx) * L2E);
    e0.y = __builtin_amdgcn_exp2f((x0.y - mx) * L2E);
    e0.z = __builtin_amdgcn_exp2f((x0.z - mx) * L2E);
    e0.w = __builtin_amdgcn_exp2f((x0.w - mx) * L2E);
    e1.x = __builtin_amdgcn_exp2f((x1.x - mx) * L2E);
    e1.y = __builtin_amdgcn_exp2f((x1.y - mx) * L2E);
    e1.z = __builtin_amdgcn_exp2f((x1.z - mx) * L2E);
    e1.w = __builtin_amdgcn_exp2f((x1.w - mx) * L2E);
    float sum = e0.x + e0.y + e0.z + e0.w + e1.x + e1.y + e1.z + e1.w;
#pragma unroll
    for (int off = 32; off; off >>= 1) sum += __shfl_xor(sum, off, 64);
    if (lane == 0) red[4 + wv] = sum;
    __syncthreads();
    sum = red[4] + red[5] + red[6] + red[7];
    float inv = 1.0f / sum;
    e0.x *= inv; e0.y *= inv; e0.z *= inv; e0.w *= inv;
    e1.x *= inv; e1.y *= inv; e1.z *= inv; e1.w *= inv;
    row[t]       = e0;
    row[t + 256] = e1;
}

__global__ __launch_bounds__(256) void k_zero(float* __restrict__ context) {
    int b = blockIdx.x, t = threadIdx.x;
    float4 z = {0.f, 0.f, 0.f, 0.f};
    ((float4*)(context + (size_t)b * ENC_HID))[t] = z;
}

__global__ __launch_bounds__(256) void k_context_atomic(const float* __restrict__ enc_outs,
                                                        const float* __restrict__ weights,
                                                        float* __restrict__ context) {
    __shared__ float wl[64];
    int b     = blockIdx.x >> 5;
    int chunk = blockIdx.x & 31;
    int s0    = chunk * 64;
    int t     = threadIdx.x;
    if (t < 64) wl[t] = weights[(size_t)b * SEQ + s0 + t];
    __syncthreads();
    const float4* base = (const float4*)enc_outs;
    float4 acc = {0.f, 0.f, 0.f, 0.f};
#pragma unroll 4
    for (int i = 0; i < 64; ++i) {
        size_t idx = ((size_t)(s0 + i) * BATCH + b) * (ENC_HID / 4) + t;
        float4 e = base[idx];
        float w = wl[i];
        acc.x += w * e.x; acc.y += w * e.y; acc.z += w * e.z; acc.w += w * e.w;
    }
    float* dst = context + (size_t)b * ENC_HID + t * 4;
    atomicAdd(dst + 0, acc.x);
    atomicAdd(dst + 1, acc.y);
    atomicAdd(dst + 2, acc.z);
    atomicAdd(dst + 3, acc.w);
}

// ---------------------------------------------------------------------------
extern "C" void kernel_launch(void* const* d_in, const int* in_sizes, int n_in,
                              void* d_out, int out_size, void* d_ws, size_t ws_size,
                              hipStream_t stream) {
    const float* dec_out  = (const float*)d_in[0];   // (B, DEC_HID)
    const float* enc_outs = (const float*)d_in[1];   // (SEQ, B, ENC_HID)
    const float* enc_att  = (const float*)d_in[2];   // (SEQ, B, ATT_D)
    const float* W_dec    = (const float*)d_in[3];   // (ATT_D, DEC_HID)
    const float* att_v    = (const float*)d_in[4];   // (ATT_D,)

    float* out     = (float*)d_out;
    float* context = out;                          // B*ENC_HID floats
    float* weights = out + BATCH * ENC_HID;        // B*SEQ floats

    float* dec_att = (float*)d_ws;                               // B*ATT_D
    float* pctx    = dec_att + (size_t)BATCH * ATT_D;            // B*NCHUNK*ENC_HID
    float* maxsum  = pctx + (size_t)BATCH * NCHUNK * ENC_HID;    // B*NCHUNK*2

    // 1. dec_att = dec_out @ W_dec^T
    k_dec_att<<<(BATCH * ATT_D) / 4, 256, 0, stream>>>(dec_out, W_dec, dec_att);

    size_t need = ((size_t)BATCH * ATT_D
                 + (size_t)BATCH * NCHUNK * ENC_HID
                 + (size_t)BATCH * NCHUNK * 2) * sizeof(float);
    if (ws_size >= need) {
        // 2. fused scores + local softmax + partial context (4096 blocks)
        k_fused<<<BATCH * NCHUNK, 256, 0, stream>>>(enc_att, enc_outs, dec_att, att_v,
                                                    weights, pctx, maxsum);
        // 3. combine + normalize
        k_final<<<BATCH, 256, 0, stream>>>(pctx, maxsum, context, weights);
    } else {
        k_scores<<<(SEQ * BATCH) / 4, 256, 0, stream>>>(enc_att, dec_att, att_v, weights);
        k_softmax<<<BATCH, 256, 0, stream>>>(weights);
        k_zero<<<BATCH, 256, 0, stream>>>(context);
        k_context_atomic<<<2048, 256, 0, stream>>>(enc_outs, weights, context);
    }
}

// Round 6
// 148.008 us; speedup vs baseline: 1.1857x; 1.1857x over previous
//
#include <hip/hip_runtime.h>

#define SEQ     2048
#define BATCH   64
#define ENC_HID 1024
#define DEC_HID 1024
#define ATT_D   512
#define L2E     1.4426950408889634f

// ---------------------------------------------------------------------------
// fast tanh: tanh(x) = 1 - 2/(1 + exp(2x)); saturates correctly for large |x|
__device__ __forceinline__ float fast_tanh(float x) {
    float e = __builtin_amdgcn_exp2f(x * 2.8853900817779268f);
    return 1.0f - 2.0f * __builtin_amdgcn_rcpf(1.0f + e);
}

// non-temporal float4 load (bypass cache retention for stream-once data).
// __builtin_nontemporal_load needs a native scalar/vector pointer, not
// HIP_vector_type — go through a clang ext_vector_type.
typedef float floatv4 __attribute__((ext_vector_type(4)));
__device__ __forceinline__ float4 ntload4(const float4* p) {
    floatv4 v = __builtin_nontemporal_load((const floatv4*)p);
    return make_float4(v.x, v.y, v.z, v.w);
}

// ---------------------------------------------------------------------------
// Kernel 1: dec_att[b][a] = sum_k dec_out[b][k] * W_dec[a][k]  (one wave/output)
__global__ __launch_bounds__(256) void k_dec_att(const float* __restrict__ dec_out,
                                                 const float* __restrict__ W_dec,
                                                 float* __restrict__ dec_att) {
    int w    = blockIdx.x * 4 + (threadIdx.x >> 6);
    int lane = threadIdx.x & 63;
    int b = w >> 9;
    int a = w & (ATT_D - 1);
    const float4* wd = (const float4*)(W_dec + (size_t)a * DEC_HID);
    const float4* dd = (const float4*)(dec_out + (size_t)b * DEC_HID);
    float acc = 0.f;
#pragma unroll
    for (int j = 0; j < 4; ++j) {
        int idx = j * 64 + lane;
        float4 x = wd[idx];
        float4 y = dd[idx];
        acc += x.x * y.x + x.y * y.y + x.z * y.z + x.w * y.w;
    }
#pragma unroll
    for (int off = 32; off; off >>= 1) acc += __shfl_xor(acc, off, 64);
    if (lane == 0) dec_att[(size_t)b * ATT_D + a] = acc;
}

// ---------------------------------------------------------------------------
// Kernel 2: scores[b][s] = sum_a tanh(enc_att[s][b][a] + dec_att[b][a]) * att_v[a]
// one wave per (s,b); enc_att is stream-once -> non-temporal loads.
__global__ __launch_bounds__(256) void k_scores(const float* __restrict__ enc_att,
                                                const float* __restrict__ dec_att,
                                                const float* __restrict__ att_v,
                                                float* __restrict__ scores) {
    int w    = blockIdx.x * 4 + (threadIdx.x >> 6);
    int lane = threadIdx.x & 63;
    int b = w & (BATCH - 1);
    int s = w >> 6;
    const float4* ea = (const float4*)(enc_att + ((size_t)s * BATCH + b) * ATT_D);
    const float4* da = (const float4*)(dec_att + (size_t)b * ATT_D);
    const float4* av = (const float4*)att_v;
    float acc = 0.f;
#pragma unroll
    for (int j = 0; j < 2; ++j) {
        int idx = j * 64 + lane;
        float4 e = ntload4(&ea[idx]);
        float4 d = da[idx];
        float4 v = av[idx];
        acc += fast_tanh(e.x + d.x) * v.x;
        acc += fast_tanh(e.y + d.y) * v.y;
        acc += fast_tanh(e.z + d.z) * v.z;
        acc += fast_tanh(e.w + d.w) * v.w;
    }
#pragma unroll
    for (int off = 32; off; off >>= 1) acc += __shfl_xor(acc, off, 64);
    if (lane == 0) scores[(size_t)b * SEQ + s] = acc;
}

// ---------------------------------------------------------------------------
// Kernel 3: in-place row softmax. one block (256 thr) per batch row of 2048.
__global__ __launch_bounds__(256) void k_softmax(float* __restrict__ scores) {
    __shared__ float red[8];
    int b = blockIdx.x;
    int t = threadIdx.x;
    int lane = t & 63, wv = t >> 6;
    float4* row = (float4*)(scores + (size_t)b * SEQ);
    float4 x0 = row[t];
    float4 x1 = row[t + 256];
    float mx = fmaxf(fmaxf(fmaxf(x0.x, x0.y), fmaxf(x0.z, x0.w)),
                     fmaxf(fmaxf(x1.x, x1.y), fmaxf(x1.z, x1.w)));
#pragma unroll
    for (int off = 32; off; off >>= 1) mx = fmaxf(mx, __shfl_xor(mx, off, 64));
    if (lane == 0) red[wv] = mx;
    __syncthreads();
    mx = fmaxf(fmaxf(red[0], red[1]), fmaxf(red[2], red[3]));

    float4 e0, e1;
    e0.x = __builtin_amdgcn_exp2f((x0.x - mx) * L2E);
    e0.y = __builtin_amdgcn_exp2f((x0.y - mx) * L2E);
    e0.z = __builtin_amdgcn_exp2f((x0.z - mx) * L2E);
    e0.w = __builtin_amdgcn_exp2f((x0.w - mx) * L2E);
    e1.x = __builtin_amdgcn_exp2f((x1.x - mx) * L2E);
    e1.y = __builtin_amdgcn_exp2f((x1.y - mx) * L2E);
    e1.z = __builtin_amdgcn_exp2f((x1.z - mx) * L2E);
    e1.w = __builtin_amdgcn_exp2f((x1.w - mx) * L2E);
    float sum = e0.x + e0.y + e0.z + e0.w + e1.x + e1.y + e1.z + e1.w;
#pragma unroll
    for (int off = 32; off; off >>= 1) sum += __shfl_xor(sum, off, 64);
    if (lane == 0) red[4 + wv] = sum;
    __syncthreads();
    sum = red[4] + red[5] + red[6] + red[7];
    float inv = 1.0f / sum;
    e0.x *= inv; e0.y *= inv; e0.z *= inv; e0.w *= inv;
    e1.x *= inv; e1.y *= inv; e1.z *= inv; e1.w *= inv;
    row[t]       = e0;
    row[t + 256] = e1;
}

// ---------------------------------------------------------------------------
// Kernel 4a: partial context. block = (b, s-chunk of 64). 256 thr * float4 = 1024 h.
// enc_outs is stream-once -> non-temporal loads. partial stays cached.
__global__ __launch_bounds__(256) void k_context_partial(const float* __restrict__ enc_outs,
                                                         const float* __restrict__ weights,
                                                         float* __restrict__ partial) {
    __shared__ float wl[64];
    int b     = blockIdx.x >> 5;
    int chunk = blockIdx.x & 31;
    int s0    = chunk * 64;
    int t     = threadIdx.x;
    if (t < 64) wl[t] = weights[(size_t)b * SEQ + s0 + t];
    __syncthreads();
    const float4* base = (const float4*)enc_outs;
    float4 acc = {0.f, 0.f, 0.f, 0.f};
#pragma unroll 4
    for (int i = 0; i < 64; ++i) {
        int s = s0 + i;
        size_t idx = ((size_t)s * BATCH + b) * (ENC_HID / 4) + t;
        float4 e = ntload4(&base[idx]);
        float w = wl[i];
        acc.x += w * e.x; acc.y += w * e.y; acc.z += w * e.z; acc.w += w * e.w;
    }
    ((float4*)(partial + (size_t)blockIdx.x * ENC_HID))[t] = acc;
}

// Kernel 4b: reduce 32 partials per (b,h)
__global__ __launch_bounds__(256) void k_context_reduce(const float* __restrict__ partial,
                                                        float* __restrict__ context) {
    int b = blockIdx.x;
    int t = threadIdx.x;
    float4 acc = {0.f, 0.f, 0.f, 0.f};
#pragma unroll 8
    for (int c = 0; c < 32; ++c) {
        float4 e = ((const float4*)(partial + ((size_t)b * 32 + c) * ENC_HID))[t];
        acc.x += e.x; acc.y += e.y; acc.z += e.z; acc.w += e.w;
    }
    ((float4*)(context + (size_t)b * ENC_HID))[t] = acc;
}

// ---- fallback path (small ws): zero + atomic accumulate -------------------
__global__ __launch_bounds__(256) void k_zero(float* __restrict__ context) {
    int b = blockIdx.x, t = threadIdx.x;
    float4 z = {0.f, 0.f, 0.f, 0.f};
    ((float4*)(context + (size_t)b * ENC_HID))[t] = z;
}

__global__ __launch_bounds__(256) void k_context_atomic(const float* __restrict__ enc_outs,
                                                        const float* __restrict__ weights,
                                                        float* __restrict__ context) {
    __shared__ float wl[64];
    int b     = blockIdx.x >> 5;
    int chunk = blockIdx.x & 31;
    int s0    = chunk * 64;
    int t     = threadIdx.x;
    if (t < 64) wl[t] = weights[(size_t)b * SEQ + s0 + t];
    __syncthreads();
    const float4* base = (const float4*)enc_outs;
    float4 acc = {0.f, 0.f, 0.f, 0.f};
#pragma unroll 4
    for (int i = 0; i < 64; ++i) {
        int s = s0 + i;
        size_t idx = ((size_t)s * BATCH + b) * (ENC_HID / 4) + t;
        float4 e = ntload4(&base[idx]);
        float w = wl[i];
        acc.x += w * e.x; acc.y += w * e.y; acc.z += w * e.z; acc.w += w * e.w;
    }
    float* dst = context + (size_t)b * ENC_HID + t * 4;
    atomicAdd(dst + 0, acc.x);
    atomicAdd(dst + 1, acc.y);
    atomicAdd(dst + 2, acc.z);
    atomicAdd(dst + 3, acc.w);
}

// ---------------------------------------------------------------------------
extern "C" void kernel_launch(void* const* d_in, const int* in_sizes, int n_in,
                              void* d_out, int out_size, void* d_ws, size_t ws_size,
                              hipStream_t stream) {
    const float* dec_out  = (const float*)d_in[0];   // (B, DEC_HID)
    const float* enc_outs = (const float*)d_in[1];   // (SEQ, B, ENC_HID)
    const float* enc_att  = (const float*)d_in[2];   // (SEQ, B, ATT_D)
    const float* W_dec    = (const float*)d_in[3];   // (ATT_D, DEC_HID)
    const float* att_v    = (const float*)d_in[4];   // (ATT_D,)

    float* out     = (float*)d_out;
    float* context = out;                          // B*ENC_HID floats
    float* weights = out + BATCH * ENC_HID;        // B*SEQ floats (scores in-place)

    float* dec_att = (float*)d_ws;                 // B*ATT_D floats
    float* partial = (float*)d_ws + BATCH * ATT_D; // 2048*ENC_HID floats

    // 1. dec_att = dec_out @ W_dec^T  (one wave per output)
    k_dec_att<<<(BATCH * ATT_D) / 4, 256, 0, stream>>>(dec_out, W_dec, dec_att);

    // 2. scores (written into the weights slot of d_out)
    k_scores<<<(SEQ * BATCH) / 4, 256, 0, stream>>>(enc_att, dec_att, att_v, weights);

    // 3. softmax in-place -> weights
    k_softmax<<<BATCH, 256, 0, stream>>>(weights);

    // 4. context
    size_t need = ((size_t)BATCH * ATT_D + (size_t)2048 * ENC_HID) * sizeof(float);
    if (ws_size >= need) {
        k_context_partial<<<2048, 256, 0, stream>>>(enc_outs, weights, partial);
        k_context_reduce<<<BATCH, 256, 0, stream>>>(partial, context);
    } else {
        k_zero<<<BATCH, 256, 0, stream>>>(context);
        k_context_atomic<<<2048, 256, 0, stream>>>(enc_outs, weights, context);
    }
}

// Round 8
// 146.613 us; speedup vs baseline: 1.1970x; 1.0095x over previous
//
#include <hip/hip_runtime.h>

#define SEQ     2048
#define BATCH   64
#define ENC_HID 1024
#define DEC_HID 1024
#define ATT_D   512
#define CHUNK   64
#define NCHUNK  (SEQ / CHUNK)   /* 32 */
#define L2E     1.4426950408889634f

// ---------------------------------------------------------------------------
// fast tanh: tanh(x) = 1 - 2/(1 + exp(2x)); saturates correctly for large |x|
__device__ __forceinline__ float fast_tanh(float x) {
    float e = __builtin_amdgcn_exp2f(x * 2.8853900817779268f);
    return 1.0f - 2.0f * __builtin_amdgcn_rcpf(1.0f + e);
}

// non-temporal float4 load (bypass cache retention for stream-once data)
typedef float floatv4 __attribute__((ext_vector_type(4)));
__device__ __forceinline__ float4 ntload4(const float4* p) {
    floatv4 v = __builtin_nontemporal_load((const floatv4*)p);
    return make_float4(v.x, v.y, v.z, v.w);
}

// ---------------------------------------------------------------------------
// Kernel 1: dec_att[b][a] = sum_k dec_out[b][k] * W_dec[a][k]  (one wave/output)
__global__ __launch_bounds__(256) void k_dec_att(const float* __restrict__ dec_out,
                                                 const float* __restrict__ W_dec,
                                                 float* __restrict__ dec_att) {
    int w    = blockIdx.x * 4 + (threadIdx.x >> 6);
    int lane = threadIdx.x & 63;
    int b = w >> 9;
    int a = w & (ATT_D - 1);
    const float4* wd = (const float4*)(W_dec + (size_t)a * DEC_HID);
    const float4* dd = (const float4*)(dec_out + (size_t)b * DEC_HID);
    float acc = 0.f;
#pragma unroll
    for (int j = 0; j < 4; ++j) {
        int idx = j * 64 + lane;
        float4 x = wd[idx];
        float4 y = dd[idx];
        acc += x.x * y.x + x.y * y.y + x.z * y.z + x.w * y.w;
    }
#pragma unroll
    for (int off = 32; off; off >>= 1) acc += __shfl_xor(acc, off, 64);
    if (lane == 0) dec_att[(size_t)b * ATT_D + a] = acc;
}

// ---------------------------------------------------------------------------
// Kernel 2: scores[b][s] = sum_a tanh(enc_att[s][b][a] + dec_att[b][a]) * att_v[a]
// one wave per (s,b); enc_att is stream-once -> non-temporal loads.
__global__ __launch_bounds__(256) void k_scores(const float* __restrict__ enc_att,
                                                const float* __restrict__ dec_att,
                                                const float* __restrict__ att_v,
                                                float* __restrict__ scores) {
    int w    = blockIdx.x * 4 + (threadIdx.x >> 6);
    int lane = threadIdx.x & 63;
    int b = w & (BATCH - 1);
    int s = w >> 6;
    const float4* ea = (const float4*)(enc_att + ((size_t)s * BATCH + b) * ATT_D);
    const float4* da = (const float4*)(dec_att + (size_t)b * ATT_D);
    const float4* av = (const float4*)att_v;
    float acc = 0.f;
#pragma unroll
    for (int j = 0; j < 2; ++j) {
        int idx = j * 64 + lane;
        float4 e = ntload4(&ea[idx]);
        float4 d = da[idx];
        float4 v = av[idx];
        acc += fast_tanh(e.x + d.x) * v.x;
        acc += fast_tanh(e.y + d.y) * v.y;
        acc += fast_tanh(e.z + d.z) * v.z;
        acc += fast_tanh(e.w + d.w) * v.w;
    }
#pragma unroll
    for (int off = 32; off; off >>= 1) acc += __shfl_xor(acc, off, 64);
    if (lane == 0) scores[(size_t)b * SEQ + s] = acc;
}

// ---------------------------------------------------------------------------
// Kernel 3: partial context with chunk-local softmax stats (flash style).
// block = (b, s-chunk of 64). Reads RAW scores; no global softmax needed first.
__global__ __launch_bounds__(256) void k_context_partial(
        const float* __restrict__ enc_outs,
        const float* __restrict__ scores_raw,
        float* __restrict__ partial,          // (B*NCHUNK, ENC_HID) unnormalized
        float* __restrict__ maxsum)           // (B*NCHUNK, 2)
{
    __shared__ float wl[CHUNK];
    int bid   = blockIdx.x;
    int b     = bid >> 5;
    int chunk = bid & (NCHUNK - 1);
    int s0    = chunk * CHUNK;
    int t     = threadIdx.x;
    int wv    = t >> 6, lane = t & 63;

    // wave 0: chunk-local max / expsum over the 64 raw scores
    if (wv == 0) {
        float v = scores_raw[(size_t)b * SEQ + s0 + lane];
        float m = v;
#pragma unroll
        for (int off = 32; off; off >>= 1) m = fmaxf(m, __shfl_xor(m, off, 64));
        float u = __builtin_amdgcn_exp2f((v - m) * L2E);
        wl[lane] = u;
        float ssum = u;
#pragma unroll
        for (int off = 32; off; off >>= 1) ssum += __shfl_xor(ssum, off, 64);
        if (lane == 0) {
            maxsum[2 * bid]     = m;
            maxsum[2 * bid + 1] = ssum;
        }
    }
    __syncthreads();

    // unnormalized exp-weighted partial context (enc_outs stream-once -> nt)
    const float4* base = (const float4*)enc_outs;
    float4 acc = {0.f, 0.f, 0.f, 0.f};
#pragma unroll 4
    for (int i = 0; i < CHUNK; ++i) {
        size_t idx = ((size_t)(s0 + i) * BATCH + b) * (ENC_HID / 4) + t;
        float4 e = ntload4(&base[idx]);
        float w = wl[i];
        acc.x += w * e.x; acc.y += w * e.y; acc.z += w * e.z; acc.w += w * e.w;
    }
    ((float4*)(partial + (size_t)bid * ENC_HID))[t] = acc;
}

// ---------------------------------------------------------------------------
// Kernel 4: per b — flash combine of NCHUNK partials -> context,
//           and normalize raw scores -> weights.
__global__ __launch_bounds__(256) void k_final(
        const float* __restrict__ partial,
        const float* __restrict__ maxsum,
        float* __restrict__ context,   // (B, ENC_HID)
        float* __restrict__ weights)   // (B, SEQ): raw scores in, softmax out
{
    __shared__ float scale[NCHUNK];
    __shared__ float gv[2];
    int b = blockIdx.x;
    int t = threadIdx.x;
    int wv = t >> 6, lane = t & 63;

    if (wv == 0) {
        float m = (lane < NCHUNK) ? maxsum[2 * (b * NCHUNK + lane)]     : -3.4e38f;
        float s = (lane < NCHUNK) ? maxsum[2 * (b * NCHUNK + lane) + 1] : 0.f;
        float gm = m;
#pragma unroll
        for (int off = 32; off; off >>= 1) gm = fmaxf(gm, __shfl_xor(gm, off, 64));
        float sc_ = __builtin_amdgcn_exp2f((m - gm) * L2E);
        float e = s * sc_;
#pragma unroll
        for (int off = 32; off; off >>= 1) e += __shfl_xor(e, off, 64);
        if (lane < NCHUNK) scale[lane] = sc_;
        if (lane == 0) { gv[0] = gm; gv[1] = 1.0f / e; }
    }
    __syncthreads();
    float gm = gv[0], inv = gv[1];

    float4 acc = {0.f, 0.f, 0.f, 0.f};
#pragma unroll 8
    for (int c = 0; c < NCHUNK; ++c) {
        float4 e = ((const float4*)(partial + ((size_t)b * NCHUNK + c) * ENC_HID))[t];
        float s = scale[c];
        acc.x += s * e.x; acc.y += s * e.y; acc.z += s * e.z; acc.w += s * e.w;
    }
    acc.x *= inv; acc.y *= inv; acc.z *= inv; acc.w *= inv;
    ((float4*)(context + (size_t)b * ENC_HID))[t] = acc;

    float4* wrow = (float4*)(weights + (size_t)b * SEQ);
#pragma unroll
    for (int j = 0; j < 2; ++j) {
        float4 x = wrow[j * 256 + t];
        x.x = __builtin_amdgcn_exp2f((x.x - gm) * L2E) * inv;
        x.y = __builtin_amdgcn_exp2f((x.y - gm) * L2E) * inv;
        x.z = __builtin_amdgcn_exp2f((x.z - gm) * L2E) * inv;
        x.w = __builtin_amdgcn_exp2f((x.w - gm) * L2E) * inv;
        wrow[j * 256 + t] = x;
    }
}

// ---- fallback path (small ws): softmax + zero + atomic accumulate ---------
__global__ __launch_bounds__(256) void k_softmax(float* __restrict__ scores) {
    __shared__ float red[8];
    int b = blockIdx.x;
    int t = threadIdx.x;
    int lane = t & 63, wv = t >> 6;
    float4* row = (float4*)(scores + (size_t)b * SEQ);
    float4 x0 = row[t];
    float4 x1 = row[t + 256];
    float mx = fmaxf(fmaxf(fmaxf(x0.x, x0.y), fmaxf(x0.z, x0.w)),
                     fmaxf(fmaxf(x1.x, x1.y), fmaxf(x1.z, x1.w)));
#pragma unroll
    for (int off = 32; off; off >>= 1) mx = fmaxf(mx, __shfl_xor(mx, off, 64));
    if (lane == 0) red[wv] = mx;
    __syncthreads();
    mx = fmaxf(fmaxf(red[0], red[1]), fmaxf(red[2], red[3]));
    float4 e0, e1;
    e0.x = __builtin_amdgcn_exp2f((x0.x - mx) * L2E);
    e0.y = __builtin_amdgcn_exp2f((x0.y - mx) * L2E);
    e0.z = __builtin_amdgcn_exp2f((x0.z - mx) * L2E);
    e0.w = __builtin_amdgcn_exp2f((x0.w - mx) * L2E);
    e1.x = __builtin_amdgcn_exp2f((x1.x - mx) * L2E);
    e1.y = __builtin_amdgcn_exp2f((x1.y - mx) * L2E);
    e1.z = __builtin_amdgcn_exp2f((x1.z - mx) * L2E);
    e1.w = __builtin_amdgcn_exp2f((x1.w - mx) * L2E);
    float sum = e0.x + e0.y + e0.z + e0.w + e1.x + e1.y + e1.z + e1.w;
#pragma unroll
    for (int off = 32; off; off >>= 1) sum += __shfl_xor(sum, off, 64);
    if (lane == 0) red[4 + wv] = sum;
    __syncthreads();
    sum = red[4] + red[5] + red[6] + red[7];
    float inv = 1.0f / sum;
    e0.x *= inv; e0.y *= inv; e0.z *= inv; e0.w *= inv;
    e1.x *= inv; e1.y *= inv; e1.z *= inv; e1.w *= inv;
    row[t]       = e0;
    row[t + 256] = e1;
}

__global__ __launch_bounds__(256) void k_zero(float* __restrict__ context) {
    int b = blockIdx.x, t = threadIdx.x;
    float4 z = {0.f, 0.f, 0.f, 0.f};
    ((float4*)(context + (size_t)b * ENC_HID))[t] = z;
}

__global__ __launch_bounds__(256) void k_context_atomic(const float* __restrict__ enc_outs,
                                                        const float* __restrict__ weights,
                                                        float* __restrict__ context) {
    __shared__ float wl[64];
    int b     = blockIdx.x >> 5;
    int chunk = blockIdx.x & 31;
    int s0    = chunk * 64;
    int t     = threadIdx.x;
    if (t < 64) wl[t] = weights[(size_t)b * SEQ + s0 + t];
    __syncthreads();
    const float4* base = (const float4*)enc_outs;
    float4 acc = {0.f, 0.f, 0.f, 0.f};
#pragma unroll 4
    for (int i = 0; i < 64; ++i) {
        size_t idx = ((size_t)(s0 + i) * BATCH + b) * (ENC_HID / 4) + t;
        float4 e = ntload4(&base[idx]);
        float w = wl[i];
        acc.x += w * e.x; acc.y += w * e.y; acc.z += w * e.z; acc.w += w * e.w;
    }
    float* dst = context + (size_t)b * ENC_HID + t * 4;
    atomicAdd(dst + 0, acc.x);
    atomicAdd(dst + 1, acc.y);
    atomicAdd(dst + 2, acc.z);
    atomicAdd(dst + 3, acc.w);
}

// ---------------------------------------------------------------------------
extern "C" void kernel_launch(void* const* d_in, const int* in_sizes, int n_in,
                              void* d_out, int out_size, void* d_ws, size_t ws_size,
                              hipStream_t stream) {
    const float* dec_out  = (const float*)d_in[0];   // (B, DEC_HID)
    const float* enc_outs = (const float*)d_in[1];   // (SEQ, B, ENC_HID)
    const float* enc_att  = (const float*)d_in[2];   // (SEQ, B, ATT_D)
    const float* W_dec    = (const float*)d_in[3];   // (ATT_D, DEC_HID)
    const float* att_v    = (const float*)d_in[4];   // (ATT_D,)

    float* out     = (float*)d_out;
    float* context = out;                          // B*ENC_HID floats
    float* weights = out + BATCH * ENC_HID;        // B*SEQ floats (raw scores first)

    float* dec_att = (float*)d_ws;                                // B*ATT_D
    float* partial = dec_att + (size_t)BATCH * ATT_D;             // B*NCHUNK*ENC_HID
    float* maxsum  = partial + (size_t)BATCH * NCHUNK * ENC_HID;  // B*NCHUNK*2

    // 1. dec_att = dec_out @ W_dec^T
    k_dec_att<<<(BATCH * ATT_D) / 4, 256, 0, stream>>>(dec_out, W_dec, dec_att);

    // 2. raw scores into the weights slot
    k_scores<<<(SEQ * BATCH) / 4, 256, 0, stream>>>(enc_att, dec_att, att_v, weights);

    size_t need = ((size_t)BATCH * ATT_D
                 + (size_t)BATCH * NCHUNK * ENC_HID
                 + (size_t)BATCH * NCHUNK * 2) * sizeof(float);
    if (ws_size >= need) {
        // 3. partial context from raw scores (chunk-local softmax stats)
        k_context_partial<<<BATCH * NCHUNK, 256, 0, stream>>>(enc_outs, weights,
                                                              partial, maxsum);
        // 4. flash combine -> context; normalize scores -> weights
        k_final<<<BATCH, 256, 0, stream>>>(partial, maxsum, context, weights);
    } else {
        k_softmax<<<BATCH, 256, 0, stream>>>(weights);
        k_zero<<<BATCH, 256, 0, stream>>>(context);
        k_context_atomic<<<2048, 256, 0, stream>>>(enc_outs, weights, context);
    }
}

// Round 9
// 140.229 us; speedup vs baseline: 1.2515x; 1.0455x over previous
//
#include <hip/hip_runtime.h>

#define SEQ     2048
#define BATCH   64
#define ENC_HID 1024
#define DEC_HID 1024
#define ATT_D   512
#define CHUNK   128
#define NCHUNK  (SEQ / CHUNK)   /* 16 */
#define L2E     1.4426950408889634f

// ---------------------------------------------------------------------------
// fast tanh: tanh(x) = 1 - 2/(1 + exp(2x)); saturates correctly for large |x|
__device__ __forceinline__ float fast_tanh(float x) {
    float e = __builtin_amdgcn_exp2f(x * 2.8853900817779268f);
    return 1.0f - 2.0f * __builtin_amdgcn_rcpf(1.0f + e);
}

// non-temporal float4 load (bypass cache retention for stream-once data)
typedef float floatv4 __attribute__((ext_vector_type(4)));
__device__ __forceinline__ float4 ntload4(const float4* p) {
    floatv4 v = __builtin_nontemporal_load((const floatv4*)p);
    return make_float4(v.x, v.y, v.z, v.w);
}

// ---------------------------------------------------------------------------
// Kernel 1: dec_att[b][a] = sum_k dec_out[b][k] * W_dec[a][k]  (one wave/output)
__global__ __launch_bounds__(256) void k_dec_att(const float* __restrict__ dec_out,
                                                 const float* __restrict__ W_dec,
                                                 float* __restrict__ dec_att) {
    int w    = blockIdx.x * 4 + (threadIdx.x >> 6);
    int lane = threadIdx.x & 63;
    int b = w >> 9;
    int a = w & (ATT_D - 1);
    const float4* wd = (const float4*)(W_dec + (size_t)a * DEC_HID);
    const float4* dd = (const float4*)(dec_out + (size_t)b * DEC_HID);
    float acc = 0.f;
#pragma unroll
    for (int j = 0; j < 4; ++j) {
        int idx = j * 64 + lane;
        float4 x = wd[idx];
        float4 y = dd[idx];
        acc += x.x * y.x + x.y * y.y + x.z * y.z + x.w * y.w;
    }
#pragma unroll
    for (int off = 32; off; off >>= 1) acc += __shfl_xor(acc, off, 64);
    if (lane == 0) dec_att[(size_t)b * ATT_D + a] = acc;
}

// ---------------------------------------------------------------------------
// Kernel 2: scores for TWO adjacent s per wave (same b) — 4 float4 loads in
// flight, two independent reduce chains, one float2 write.
__global__ __launch_bounds__(256) void k_scores(const float* __restrict__ enc_att,
                                                const float* __restrict__ dec_att,
                                                const float* __restrict__ att_v,
                                                float* __restrict__ scores) {
    int w    = blockIdx.x * 4 + (threadIdx.x >> 6);   // wave id in [0, 65536)
    int lane = threadIdx.x & 63;
    int b  = w & (BATCH - 1);
    int sp = w >> 6;                                  // s-pair in [0, 1024)
    int s  = sp * 2;
    const float4* ea0 = (const float4*)(enc_att + ((size_t)s * BATCH + b) * ATT_D);
    const float4* ea1 = (const float4*)(enc_att + ((size_t)(s + 1) * BATCH + b) * ATT_D);
    const float4* da  = (const float4*)(dec_att + (size_t)b * ATT_D);
    const float4* av  = (const float4*)att_v;

    float4 d0 = da[lane],      d1 = da[64 + lane];
    float4 v0 = av[lane],      v1 = av[64 + lane];
    float4 a0 = ntload4(&ea0[lane]);
    float4 a1 = ntload4(&ea0[64 + lane]);
    float4 b0 = ntload4(&ea1[lane]);
    float4 b1 = ntload4(&ea1[64 + lane]);

    float acc0 = fast_tanh(a0.x + d0.x) * v0.x + fast_tanh(a0.y + d0.y) * v0.y
               + fast_tanh(a0.z + d0.z) * v0.z + fast_tanh(a0.w + d0.w) * v0.w
               + fast_tanh(a1.x + d1.x) * v1.x + fast_tanh(a1.y + d1.y) * v1.y
               + fast_tanh(a1.z + d1.z) * v1.z + fast_tanh(a1.w + d1.w) * v1.w;
    float acc1 = fast_tanh(b0.x + d0.x) * v0.x + fast_tanh(b0.y + d0.y) * v0.y
               + fast_tanh(b0.z + d0.z) * v0.z + fast_tanh(b0.w + d0.w) * v0.w
               + fast_tanh(b1.x + d1.x) * v1.x + fast_tanh(b1.y + d1.y) * v1.y
               + fast_tanh(b1.z + d1.z) * v1.z + fast_tanh(b1.w + d1.w) * v1.w;
#pragma unroll
    for (int off = 32; off; off >>= 1) {
        acc0 += __shfl_xor(acc0, off, 64);
        acc1 += __shfl_xor(acc1, off, 64);
    }
    if (lane == 0) {
        float2* dst = (float2*)(scores + (size_t)b * SEQ + s);
        *dst = make_float2(acc0, acc1);
    }
}

// ---------------------------------------------------------------------------
// Kernel 3: partial context with chunk-local softmax stats (flash style).
// block = (b, s-chunk of 128). Reads RAW scores.
__global__ __launch_bounds__(256) void k_context_partial(
        const float* __restrict__ enc_outs,
        const float* __restrict__ scores_raw,
        float* __restrict__ partial,          // (B*NCHUNK, ENC_HID) unnormalized
        float* __restrict__ maxsum)           // (B*NCHUNK, 2)
{
    __shared__ float wl[CHUNK];
    __shared__ float red[8];
    int bid   = blockIdx.x;
    int b     = bid >> 4;                 // / NCHUNK
    int chunk = bid & (NCHUNK - 1);
    int s0    = chunk * CHUNK;
    int t     = threadIdx.x;
    int wv    = t >> 6, lane = t & 63;

    // chunk-local max over 128 raw scores (threads 0..127)
    float v = (t < CHUNK) ? scores_raw[(size_t)b * SEQ + s0 + t] : -3.4e38f;
    float m = v;
#pragma unroll
    for (int off = 32; off; off >>= 1) m = fmaxf(m, __shfl_xor(m, off, 64));
    if (lane == 0) red[wv] = m;
    __syncthreads();
    m = fmaxf(red[0], red[1]);

    float u = (t < CHUNK) ? __builtin_amdgcn_exp2f((v - m) * L2E) : 0.f;
    if (t < CHUNK) wl[t] = u;
    float ss = u;
#pragma unroll
    for (int off = 32; off; off >>= 1) ss += __shfl_xor(ss, off, 64);
    if (lane == 0) red[4 + wv] = ss;
    __syncthreads();
    if (t == 0) {
        maxsum[2 * bid]     = m;
        maxsum[2 * bid + 1] = red[4] + red[5];
    }

    // unnormalized exp-weighted partial context (enc_outs stream-once -> nt)
    const float4* base = (const float4*)enc_outs;
    float4 acc = {0.f, 0.f, 0.f, 0.f};
#pragma unroll 4
    for (int i = 0; i < CHUNK; ++i) {
        size_t idx = ((size_t)(s0 + i) * BATCH + b) * (ENC_HID / 4) + t;
        float4 e = ntload4(&base[idx]);
        float w = wl[i];
        acc.x += w * e.x; acc.y += w * e.y; acc.z += w * e.z; acc.w += w * e.w;
    }
    ((float4*)(partial + (size_t)bid * ENC_HID))[t] = acc;
}

// ---------------------------------------------------------------------------
// Kernel 4: per b — flash combine of NCHUNK partials -> context,
//           and normalize raw scores -> weights.
__global__ __launch_bounds__(256) void k_final(
        const float* __restrict__ partial,
        const float* __restrict__ maxsum,
        float* __restrict__ context,   // (B, ENC_HID)
        float* __restrict__ weights)   // (B, SEQ): raw scores in, softmax out
{
    __shared__ float scale[NCHUNK];
    __shared__ float gv[2];
    int b = blockIdx.x;
    int t = threadIdx.x;
    int wv = t >> 6, lane = t & 63;

    if (wv == 0) {
        float m = (lane < NCHUNK) ? maxsum[2 * (b * NCHUNK + lane)]     : -3.4e38f;
        float s = (lane < NCHUNK) ? maxsum[2 * (b * NCHUNK + lane) + 1] : 0.f;
        float gm = m;
#pragma unroll
        for (int off = 32; off; off >>= 1) gm = fmaxf(gm, __shfl_xor(gm, off, 64));
        float sc_ = __builtin_amdgcn_exp2f((m - gm) * L2E);
        float e = s * sc_;
#pragma unroll
        for (int off = 32; off; off >>= 1) e += __shfl_xor(e, off, 64);
        if (lane < NCHUNK) scale[lane] = sc_;
        if (lane == 0) { gv[0] = gm; gv[1] = 1.0f / e; }
    }
    __syncthreads();
    float gm = gv[0], inv = gv[1];

    float4 acc = {0.f, 0.f, 0.f, 0.f};
#pragma unroll 8
    for (int c = 0; c < NCHUNK; ++c) {
        float4 e = ((const float4*)(partial + ((size_t)b * NCHUNK + c) * ENC_HID))[t];
        float s = scale[c];
        acc.x += s * e.x; acc.y += s * e.y; acc.z += s * e.z; acc.w += s * e.w;
    }
    acc.x *= inv; acc.y *= inv; acc.z *= inv; acc.w *= inv;
    ((float4*)(context + (size_t)b * ENC_HID))[t] = acc;

    float4* wrow = (float4*)(weights + (size_t)b * SEQ);
#pragma unroll
    for (int j = 0; j < 2; ++j) {
        float4 x = wrow[j * 256 + t];
        x.x = __builtin_amdgcn_exp2f((x.x - gm) * L2E) * inv;
        x.y = __builtin_amdgcn_exp2f((x.y - gm) * L2E) * inv;
        x.z = __builtin_amdgcn_exp2f((x.z - gm) * L2E) * inv;
        x.w = __builtin_amdgcn_exp2f((x.w - gm) * L2E) * inv;
        wrow[j * 256 + t] = x;
    }
}

// ---- fallback path (small ws): softmax + zero + atomic accumulate ---------
__global__ __launch_bounds__(256) void k_softmax(float* __restrict__ scores) {
    __shared__ float red[8];
    int b = blockIdx.x;
    int t = threadIdx.x;
    int lane = t & 63, wv = t >> 6;
    float4* row = (float4*)(scores + (size_t)b * SEQ);
    float4 x0 = row[t];
    float4 x1 = row[t + 256];
    float mx = fmaxf(fmaxf(fmaxf(x0.x, x0.y), fmaxf(x0.z, x0.w)),
                     fmaxf(fmaxf(x1.x, x1.y), fmaxf(x1.z, x1.w)));
#pragma unroll
    for (int off = 32; off; off >>= 1) mx = fmaxf(mx, __shfl_xor(mx, off, 64));
    if (lane == 0) red[wv] = mx;
    __syncthreads();
    mx = fmaxf(fmaxf(red[0], red[1]), fmaxf(red[2], red[3]));
    float4 e0, e1;
    e0.x = __builtin_amdgcn_exp2f((x0.x - mx) * L2E);
    e0.y = __builtin_amdgcn_exp2f((x0.y - mx) * L2E);
    e0.z = __builtin_amdgcn_exp2f((x0.z - mx) * L2E);
    e0.w = __builtin_amdgcn_exp2f((x0.w - mx) * L2E);
    e1.x = __builtin_amdgcn_exp2f((x1.x - mx) * L2E);
    e1.y = __builtin_amdgcn_exp2f((x1.y - mx) * L2E);
    e1.z = __builtin_amdgcn_exp2f((x1.z - mx) * L2E);
    e1.w = __builtin_amdgcn_exp2f((x1.w - mx) * L2E);
    float sum = e0.x + e0.y + e0.z + e0.w + e1.x + e1.y + e1.z + e1.w;
#pragma unroll
    for (int off = 32; off; off >>= 1) sum += __shfl_xor(sum, off, 64);
    if (lane == 0) red[4 + wv] = sum;
    __syncthreads();
    sum = red[4] + red[5] + red[6] + red[7];
    float inv = 1.0f / sum;
    e0.x *= inv; e0.y *= inv; e0.z *= inv; e0.w *= inv;
    e1.x *= inv; e1.y *= inv; e1.z *= inv; e1.w *= inv;
    row[t]       = e0;
    row[t + 256] = e1;
}

__global__ __launch_bounds__(256) void k_zero(float* __restrict__ context) {
    int b = blockIdx.x, t = threadIdx.x;
    float4 z = {0.f, 0.f, 0.f, 0.f};
    ((float4*)(context + (size_t)b * ENC_HID))[t] = z;
}

__global__ __launch_bounds__(256) void k_context_atomic(const float* __restrict__ enc_outs,
                                                        const float* __restrict__ weights,
                                                        float* __restrict__ context) {
    __shared__ float wl[64];
    int b     = blockIdx.x >> 5;
    int chunk = blockIdx.x & 31;
    int s0    = chunk * 64;
    int t     = threadIdx.x;
    if (t < 64) wl[t] = weights[(size_t)b * SEQ + s0 + t];
    __syncthreads();
    const float4* base = (const float4*)enc_outs;
    float4 acc = {0.f, 0.f, 0.f, 0.f};
#pragma unroll 4
    for (int i = 0; i < 64; ++i) {
        size_t idx = ((size_t)(s0 + i) * BATCH + b) * (ENC_HID / 4) + t;
        float4 e = ntload4(&base[idx]);
        float w = wl[i];
        acc.x += w * e.x; acc.y += w * e.y; acc.z += w * e.z; acc.w += w * e.w;
    }
    float* dst = context + (size_t)b * ENC_HID + t * 4;
    atomicAdd(dst + 0, acc.x);
    atomicAdd(dst + 1, acc.y);
    atomicAdd(dst + 2, acc.z);
    atomicAdd(dst + 3, acc.w);
}

// ---------------------------------------------------------------------------
extern "C" void kernel_launch(void* const* d_in, const int* in_sizes, int n_in,
                              void* d_out, int out_size, void* d_ws, size_t ws_size,
                              hipStream_t stream) {
    const float* dec_out  = (const float*)d_in[0];   // (B, DEC_HID)
    const float* enc_outs = (const float*)d_in[1];   // (SEQ, B, ENC_HID)
    const float* enc_att  = (const float*)d_in[2];   // (SEQ, B, ATT_D)
    const float* W_dec    = (const float*)d_in[3];   // (ATT_D, DEC_HID)
    const float* att_v    = (const float*)d_in[4];   // (ATT_D,)

    float* out     = (float*)d_out;
    float* context = out;                          // B*ENC_HID floats
    float* weights = out + BATCH * ENC_HID;        // B*SEQ floats (raw scores first)

    float* dec_att = (float*)d_ws;                                // B*ATT_D
    float* partial = dec_att + (size_t)BATCH * ATT_D;             // B*NCHUNK*ENC_HID
    float* maxsum  = partial + (size_t)BATCH * NCHUNK * ENC_HID;  // B*NCHUNK*2

    // 1. dec_att = dec_out @ W_dec^T
    k_dec_att<<<(BATCH * ATT_D) / 4, 256, 0, stream>>>(dec_out, W_dec, dec_att);

    // 2. raw scores into the weights slot (2 scores per wave)
    k_scores<<<(SEQ * BATCH) / 8, 256, 0, stream>>>(enc_att, dec_att, att_v, weights);

    size_t need = ((size_t)BATCH * ATT_D
                 + (size_t)BATCH * NCHUNK * ENC_HID
                 + (size_t)BATCH * NCHUNK * 2) * sizeof(float);
    if (ws_size >= need) {
        // 3. partial context from raw scores (chunk-local softmax stats)
        k_context_partial<<<BATCH * NCHUNK, 256, 0, stream>>>(enc_outs, weights,
                                                              partial, maxsum);
        // 4. flash combine -> context; normalize scores -> weights
        k_final<<<BATCH, 256, 0, stream>>>(partial, maxsum, context, weights);
    } else {
        k_softmax<<<BATCH, 256, 0, stream>>>(weights);
        k_zero<<<BATCH, 256, 0, stream>>>(context);
        k_context_atomic<<<2048, 256, 0, stream>>>(enc_outs, weights, context);
    }
}

// Round 10
// 140.163 us; speedup vs baseline: 1.2521x; 1.0005x over previous
//
#include <hip/hip_runtime.h>

#define SEQ     2048
#define BATCH   64
#define ENC_HID 1024
#define DEC_HID 1024
#define ATT_D   512
#define CHUNK   128
#define NCHUNK  (SEQ / CHUNK)   /* 16 */
#define L2E     1.4426950408889634f

// ---------------------------------------------------------------------------
// fast tanh: tanh(x) = 1 - 2/(1 + exp(2x)); saturates correctly for large |x|
__device__ __forceinline__ float fast_tanh(float x) {
    float e = __builtin_amdgcn_exp2f(x * 2.8853900817779268f);
    return 1.0f - 2.0f * __builtin_amdgcn_rcpf(1.0f + e);
}

// non-temporal float4 load (bypass cache retention for stream-once data)
typedef float floatv4 __attribute__((ext_vector_type(4)));
__device__ __forceinline__ float4 ntload4(const float4* p) {
    floatv4 v = __builtin_nontemporal_load((const floatv4*)p);
    return make_float4(v.x, v.y, v.z, v.w);
}

// ---------------------------------------------------------------------------
// Kernel 1: dec_att[b][a] = sum_k dec_out[b][k] * W_dec[a][k]  (one wave/output)
__global__ __launch_bounds__(256) void k_dec_att(const float* __restrict__ dec_out,
                                                 const float* __restrict__ W_dec,
                                                 float* __restrict__ dec_att) {
    int w    = blockIdx.x * 4 + (threadIdx.x >> 6);
    int lane = threadIdx.x & 63;
    int b = w >> 9;
    int a = w & (ATT_D - 1);
    const float4* wd = (const float4*)(W_dec + (size_t)a * DEC_HID);
    const float4* dd = (const float4*)(dec_out + (size_t)b * DEC_HID);
    float acc = 0.f;
#pragma unroll
    for (int j = 0; j < 4; ++j) {
        int idx = j * 64 + lane;
        float4 x = wd[idx];
        float4 y = dd[idx];
        acc += x.x * y.x + x.y * y.y + x.z * y.z + x.w * y.w;
    }
#pragma unroll
    for (int off = 32; off; off >>= 1) acc += __shfl_xor(acc, off, 64);
    if (lane == 0) dec_att[(size_t)b * ATT_D + a] = acc;
}

// ---------------------------------------------------------------------------
// Kernel 2: scores for FOUR adjacent s per wave (same b) — 8 float4 loads in
// flight, four interleaved reduce chains, one float4 write.
__global__ __launch_bounds__(256) void k_scores(const float* __restrict__ enc_att,
                                                const float* __restrict__ dec_att,
                                                const float* __restrict__ att_v,
                                                float* __restrict__ scores) {
    int w    = blockIdx.x * 4 + (threadIdx.x >> 6);   // wave id in [0, 32768)
    int lane = threadIdx.x & 63;
    int b  = w & (BATCH - 1);
    int sq = w >> 6;                                  // s-quad in [0, 512)
    int s  = sq * 4;
    const float4* ea0 = (const float4*)(enc_att + ((size_t)(s + 0) * BATCH + b) * ATT_D);
    const float4* ea1 = (const float4*)(enc_att + ((size_t)(s + 1) * BATCH + b) * ATT_D);
    const float4* ea2 = (const float4*)(enc_att + ((size_t)(s + 2) * BATCH + b) * ATT_D);
    const float4* ea3 = (const float4*)(enc_att + ((size_t)(s + 3) * BATCH + b) * ATT_D);
    const float4* da  = (const float4*)(dec_att + (size_t)b * ATT_D);
    const float4* av  = (const float4*)att_v;

    float4 d0 = da[lane], d1 = da[64 + lane];
    float4 v0 = av[lane], v1 = av[64 + lane];
    float4 a0 = ntload4(&ea0[lane]);
    float4 a1 = ntload4(&ea0[64 + lane]);
    float4 b0 = ntload4(&ea1[lane]);
    float4 b1 = ntload4(&ea1[64 + lane]);
    float4 c0 = ntload4(&ea2[lane]);
    float4 c1 = ntload4(&ea2[64 + lane]);
    float4 e0 = ntload4(&ea3[lane]);
    float4 e1 = ntload4(&ea3[64 + lane]);

    float acc0 = fast_tanh(a0.x + d0.x) * v0.x + fast_tanh(a0.y + d0.y) * v0.y
               + fast_tanh(a0.z + d0.z) * v0.z + fast_tanh(a0.w + d0.w) * v0.w
               + fast_tanh(a1.x + d1.x) * v1.x + fast_tanh(a1.y + d1.y) * v1.y
               + fast_tanh(a1.z + d1.z) * v1.z + fast_tanh(a1.w + d1.w) * v1.w;
    float acc1 = fast_tanh(b0.x + d0.x) * v0.x + fast_tanh(b0.y + d0.y) * v0.y
               + fast_tanh(b0.z + d0.z) * v0.z + fast_tanh(b0.w + d0.w) * v0.w
               + fast_tanh(b1.x + d1.x) * v1.x + fast_tanh(b1.y + d1.y) * v1.y
               + fast_tanh(b1.z + d1.z) * v1.z + fast_tanh(b1.w + d1.w) * v1.w;
    float acc2 = fast_tanh(c0.x + d0.x) * v0.x + fast_tanh(c0.y + d0.y) * v0.y
               + fast_tanh(c0.z + d0.z) * v0.z + fast_tanh(c0.w + d0.w) * v0.w
               + fast_tanh(c1.x + d1.x) * v1.x + fast_tanh(c1.y + d1.y) * v1.y
               + fast_tanh(c1.z + d1.z) * v1.z + fast_tanh(c1.w + d1.w) * v1.w;
    float acc3 = fast_tanh(e0.x + d0.x) * v0.x + fast_tanh(e0.y + d0.y) * v0.y
               + fast_tanh(e0.z + d0.z) * v0.z + fast_tanh(e0.w + d0.w) * v0.w
               + fast_tanh(e1.x + d1.x) * v1.x + fast_tanh(e1.y + d1.y) * v1.y
               + fast_tanh(e1.z + d1.z) * v1.z + fast_tanh(e1.w + d1.w) * v1.w;
#pragma unroll
    for (int off = 32; off; off >>= 1) {
        acc0 += __shfl_xor(acc0, off, 64);
        acc1 += __shfl_xor(acc1, off, 64);
        acc2 += __shfl_xor(acc2, off, 64);
        acc3 += __shfl_xor(acc3, off, 64);
    }
    if (lane == 0) {
        float4* dst = (float4*)(scores + (size_t)b * SEQ + s);
        *dst = make_float4(acc0, acc1, acc2, acc3);
    }
}

// ---------------------------------------------------------------------------
// Kernel 3: partial context with chunk-local softmax stats (flash style).
// block = (b, s-chunk of 128). Reads RAW scores.
__global__ __launch_bounds__(256) void k_context_partial(
        const float* __restrict__ enc_outs,
        const float* __restrict__ scores_raw,
        float* __restrict__ partial,          // (B*NCHUNK, ENC_HID) unnormalized
        float* __restrict__ maxsum)           // (B*NCHUNK, 2)
{
    __shared__ float wl[CHUNK];
    __shared__ float red[8];
    int bid   = blockIdx.x;
    int b     = bid >> 4;                 // / NCHUNK
    int chunk = bid & (NCHUNK - 1);
    int s0    = chunk * CHUNK;
    int t     = threadIdx.x;
    int wv    = t >> 6, lane = t & 63;

    // chunk-local max over 128 raw scores (threads 0..127)
    float v = (t < CHUNK) ? scores_raw[(size_t)b * SEQ + s0 + t] : -3.4e38f;
    float m = v;
#pragma unroll
    for (int off = 32; off; off >>= 1) m = fmaxf(m, __shfl_xor(m, off, 64));
    if (lane == 0) red[wv] = m;
    __syncthreads();
    m = fmaxf(red[0], red[1]);

    float u = (t < CHUNK) ? __builtin_amdgcn_exp2f((v - m) * L2E) : 0.f;
    if (t < CHUNK) wl[t] = u;
    float ss = u;
#pragma unroll
    for (int off = 32; off; off >>= 1) ss += __shfl_xor(ss, off, 64);
    if (lane == 0) red[4 + wv] = ss;
    __syncthreads();
    if (t == 0) {
        maxsum[2 * bid]     = m;
        maxsum[2 * bid + 1] = red[4] + red[5];
    }

    // unnormalized exp-weighted partial context (enc_outs stream-once -> nt)
    const float4* base = (const float4*)enc_outs;
    float4 acc = {0.f, 0.f, 0.f, 0.f};
#pragma unroll 4
    for (int i = 0; i < CHUNK; ++i) {
        size_t idx = ((size_t)(s0 + i) * BATCH + b) * (ENC_HID / 4) + t;
        float4 e = ntload4(&base[idx]);
        float w = wl[i];
        acc.x += w * e.x; acc.y += w * e.y; acc.z += w * e.z; acc.w += w * e.w;
    }
    ((float4*)(partial + (size_t)bid * ENC_HID))[t] = acc;
}

// ---------------------------------------------------------------------------
// Kernel 4: per b — flash combine of NCHUNK partials -> context,
//           and normalize raw scores -> weights.
__global__ __launch_bounds__(256) void k_final(
        const float* __restrict__ partial,
        const float* __restrict__ maxsum,
        float* __restrict__ context,   // (B, ENC_HID)
        float* __restrict__ weights)   // (B, SEQ): raw scores in, softmax out
{
    __shared__ float scale[NCHUNK];
    __shared__ float gv[2];
    int b = blockIdx.x;
    int t = threadIdx.x;
    int wv = t >> 6, lane = t & 63;

    if (wv == 0) {
        float m = (lane < NCHUNK) ? maxsum[2 * (b * NCHUNK + lane)]     : -3.4e38f;
        float s = (lane < NCHUNK) ? maxsum[2 * (b * NCHUNK + lane) + 1] : 0.f;
        float gm = m;
#pragma unroll
        for (int off = 32; off; off >>= 1) gm = fmaxf(gm, __shfl_xor(gm, off, 64));
        float sc_ = __builtin_amdgcn_exp2f((m - gm) * L2E);
        float e = s * sc_;
#pragma unroll
        for (int off = 32; off; off >>= 1) e += __shfl_xor(e, off, 64);
        if (lane < NCHUNK) scale[lane] = sc_;
        if (lane == 0) { gv[0] = gm; gv[1] = 1.0f / e; }
    }
    __syncthreads();
    float gm = gv[0], inv = gv[1];

    float4 acc = {0.f, 0.f, 0.f, 0.f};
#pragma unroll 8
    for (int c = 0; c < NCHUNK; ++c) {
        float4 e = ((const float4*)(partial + ((size_t)b * NCHUNK + c) * ENC_HID))[t];
        float s = scale[c];
        acc.x += s * e.x; acc.y += s * e.y; acc.z += s * e.z; acc.w += s * e.w;
    }
    acc.x *= inv; acc.y *= inv; acc.z *= inv; acc.w *= inv;
    ((float4*)(context + (size_t)b * ENC_HID))[t] = acc;

    float4* wrow = (float4*)(weights + (size_t)b * SEQ);
#pragma unroll
    for (int j = 0; j < 2; ++j) {
        float4 x = wrow[j * 256 + t];
        x.x = __builtin_amdgcn_exp2f((x.x - gm) * L2E) * inv;
        x.y = __builtin_amdgcn_exp2f((x.y - gm) * L2E) * inv;
        x.z = __builtin_amdgcn_exp2f((x.z - gm) * L2E) * inv;
        x.w = __builtin_amdgcn_exp2f((x.w - gm) * L2E) * inv;
        wrow[j * 256 + t] = x;
    }
}

// ---- fallback path (small ws): softmax + zero + atomic accumulate ---------
__global__ __launch_bounds__(256) void k_softmax(float* __restrict__ scores) {
    __shared__ float red[8];
    int b = blockIdx.x;
    int t = threadIdx.x;
    int lane = t & 63, wv = t >> 6;
    float4* row = (float4*)(scores + (size_t)b * SEQ);
    float4 x0 = row[t];
    float4 x1 = row[t + 256];
    float mx = fmaxf(fmaxf(fmaxf(x0.x, x0.y), fmaxf(x0.z, x0.w)),
                     fmaxf(fmaxf(x1.x, x1.y), fmaxf(x1.z, x1.w)));
#pragma unroll
    for (int off = 32; off; off >>= 1) mx = fmaxf(mx, __shfl_xor(mx, off, 64));
    if (lane == 0) red[wv] = mx;
    __syncthreads();
    mx = fmaxf(fmaxf(red[0], red[1]), fmaxf(red[2], red[3]));
    float4 e0, e1;
    e0.x = __builtin_amdgcn_exp2f((x0.x - mx) * L2E);
    e0.y = __builtin_amdgcn_exp2f((x0.y - mx) * L2E);
    e0.z = __builtin_amdgcn_exp2f((x0.z - mx) * L2E);
    e0.w = __builtin_amdgcn_exp2f((x0.w - mx) * L2E);
    e1.x = __builtin_amdgcn_exp2f((x1.x - mx) * L2E);
    e1.y = __builtin_amdgcn_exp2f((x1.y - mx) * L2E);
    e1.z = __builtin_amdgcn_exp2f((x1.z - mx) * L2E);
    e1.w = __builtin_amdgcn_exp2f((x1.w - mx) * L2E);
    float sum = e0.x + e0.y + e0.z + e0.w + e1.x + e1.y + e1.z + e1.w;
#pragma unroll
    for (int off = 32; off; off >>= 1) sum += __shfl_xor(sum, off, 64);
    if (lane == 0) red[4 + wv] = sum;
    __syncthreads();
    sum = red[4] + red[5] + red[6] + red[7];
    float inv = 1.0f / sum;
    e0.x *= inv; e0.y *= inv; e0.z *= inv; e0.w *= inv;
    e1.x *= inv; e1.y *= inv; e1.z *= inv; e1.w *= inv;
    row[t]       = e0;
    row[t + 256] = e1;
}

__global__ __launch_bounds__(256) void k_zero(float* __restrict__ context) {
    int b = blockIdx.x, t = threadIdx.x;
    float4 z = {0.f, 0.f, 0.f, 0.f};
    ((float4*)(context + (size_t)b * ENC_HID))[t] = z;
}

__global__ __launch_bounds__(256) void k_context_atomic(const float* __restrict__ enc_outs,
                                                        const float* __restrict__ weights,
                                                        float* __restrict__ context) {
    __shared__ float wl[64];
    int b     = blockIdx.x >> 5;
    int chunk = blockIdx.x & 31;
    int s0    = chunk * 64;
    int t     = threadIdx.x;
    if (t < 64) wl[t] = weights[(size_t)b * SEQ + s0 + t];
    __syncthreads();
    const float4* base = (const float4*)enc_outs;
    float4 acc = {0.f, 0.f, 0.f, 0.f};
#pragma unroll 4
    for (int i = 0; i < 64; ++i) {
        size_t idx = ((size_t)(s0 + i) * BATCH + b) * (ENC_HID / 4) + t;
        float4 e = ntload4(&base[idx]);
        float w = wl[i];
        acc.x += w * e.x; acc.y += w * e.y; acc.z += w * e.z; acc.w += w * e.w;
    }
    float* dst = context + (size_t)b * ENC_HID + t * 4;
    atomicAdd(dst + 0, acc.x);
    atomicAdd(dst + 1, acc.y);
    atomicAdd(dst + 2, acc.z);
    atomicAdd(dst + 3, acc.w);
}

// ---------------------------------------------------------------------------
extern "C" void kernel_launch(void* const* d_in, const int* in_sizes, int n_in,
                              void* d_out, int out_size, void* d_ws, size_t ws_size,
                              hipStream_t stream) {
    const float* dec_out  = (const float*)d_in[0];   // (B, DEC_HID)
    const float* enc_outs = (const float*)d_in[1];   // (SEQ, B, ENC_HID)
    const float* enc_att  = (const float*)d_in[2];   // (SEQ, B, ATT_D)
    const float* W_dec    = (const float*)d_in[3];   // (ATT_D, DEC_HID)
    const float* att_v    = (const float*)d_in[4];   // (ATT_D,)

    float* out     = (float*)d_out;
    float* context = out;                          // B*ENC_HID floats
    float* weights = out + BATCH * ENC_HID;        // B*SEQ floats (raw scores first)

    float* dec_att = (float*)d_ws;                                // B*ATT_D
    float* partial = dec_att + (size_t)BATCH * ATT_D;             // B*NCHUNK*ENC_HID
    float* maxsum  = partial + (size_t)BATCH * NCHUNK * ENC_HID;  // B*NCHUNK*2

    // 1. dec_att = dec_out @ W_dec^T
    k_dec_att<<<(BATCH * ATT_D) / 4, 256, 0, stream>>>(dec_out, W_dec, dec_att);

    // 2. raw scores into the weights slot (4 scores per wave)
    k_scores<<<(SEQ * BATCH) / 16, 256, 0, stream>>>(enc_att, dec_att, att_v, weights);

    size_t need = ((size_t)BATCH * ATT_D
                 + (size_t)BATCH * NCHUNK * ENC_HID
                 + (size_t)BATCH * NCHUNK * 2) * sizeof(float);
    if (ws_size >= need) {
        // 3. partial context from raw scores (chunk-local softmax stats)
        k_context_partial<<<BATCH * NCHUNK, 256, 0, stream>>>(enc_outs, weights,
                                                              partial, maxsum);
        // 4. flash combine -> context; normalize scores -> weights
        k_final<<<BATCH, 256, 0, stream>>>(partial, maxsum, context, weights);
    } else {
        k_softmax<<<BATCH, 256, 0, stream>>>(weights);
        k_zero<<<BATCH, 256, 0, stream>>>(context);
        k_context_atomic<<<2048, 256, 0, stream>>>(enc_outs, weights, context);
    }
}